// Round 15
// baseline (118.182 us; speedup 1.0000x reference)
//
#include <hip/hip_runtime.h>
#include <hip/hip_bf16.h>

#define LOG2E 1.44269504088896340736f

typedef __attribute__((ext_vector_type(8))) short short8;
typedef __attribute__((ext_vector_type(4))) float f32x4;
typedef __attribute__((ext_vector_type(2))) unsigned int uint2v;
typedef __attribute__((ext_vector_type(4))) unsigned int uint4v;
typedef unsigned int u32;

__device__ __forceinline__ short f2bf(float f) {
    unsigned u = __builtin_bit_cast(unsigned, f);
    unsigned r = (u + 0x7FFFu + ((u >> 16) & 1u)) >> 16;  // RNE
    return (short)r;
}

__device__ __forceinline__ float bf2f(short x) {
    unsigned u = ((unsigned)(unsigned short)x) << 16;
    return __builtin_bit_cast(float, u);
}

__device__ __forceinline__ unsigned cvt_pk_bf16(float lo, float hi) {
    unsigned r;
    asm volatile("v_cvt_pk_bf16_f32 %0, %1, %2" : "=v"(r) : "v"(lo), "v"(hi));
    return r;
}

// raw hardware exp2 (inputs bounded in [-49, 1]: no denormal/range fixup)
__device__ __forceinline__ float fexp2(float x) {
    float r;
    asm("v_exp_f32 %0, %1" : "=v"(r) : "v"(x));
    return r;
}

// ---------------- weight prep: Wb[384][256] bf16 + Wmb[256][128] bf16 ----
__global__ __launch_bounds__(64) void wprep_kernel(
    const float* __restrict__ Wq, const float* __restrict__ bq,
    const float* __restrict__ Wk, const float* __restrict__ bk,
    const float* __restrict__ Wv, const float* __restrict__ bv,
    const float* __restrict__ Wm,
    short* __restrict__ Wb, float* __restrict__ bqkv, short* __restrict__ Wmb)
{
    const int b = blockIdx.x;       // 0..383 W rows, 384 bias, 385..640 Wm rows
    const int t = threadIdx.x;
    if (b < 384) {
        const int mat = b >> 7, row = b & 127;
        const float* src = (mat == 0 ? Wq : mat == 1 ? Wk : Wv) + (size_t)row * 256;
        const float sc = (mat == 1) ? LOG2E : 1.f;
        float4 v = *(const float4*)(src + t * 4);
        uint2v pk;
        pk.x = cvt_pk_bf16(v.x * sc, v.y * sc);
        pk.y = cvt_pk_bf16(v.z * sc, v.w * sc);
        *(uint2v*)(Wb + (size_t)b * 256 + t * 4) = pk;
    } else if (b == 384) {
        for (int e = t; e < 384; e += 64) {
            const int mat = e >> 7;
            const float* bsrc = (mat == 0 ? bq : mat == 1 ? bk : bv);
            bqkv[e] = bsrc[e & 127] * (mat == 1 ? LOG2E : 1.f);
        }
    } else {
        const int row = b - 385;        // 0..255
        float2 v = *(const float2*)(Wm + (size_t)row * 128 + t * 2);
        *(u32*)(Wmb + (size_t)row * 128 + t * 2) = cvt_pk_bf16(v.x, v.y);
    }
}

// ---------------- projection: MFMA GEMM, V -> fragment-exact VTg ---------
// (unchanged R14)
__global__ __launch_bounds__(256) void proj_kernel(
    const float* __restrict__ feat, const short* __restrict__ Wb,
    const float* __restrict__ bqkv,
    short* __restrict__ Qb, short* __restrict__ Kb, short* __restrict__ VTg)
{
    __shared__ __align__(16) short Xs[16 * 256];   // 8 KB, swizzled
    __shared__ __align__(16) short VTs[128 * 16];  // 4 KB
    const int t = threadIdx.x;
    const int blk = blockIdx.x;        // 512 blocks
    const int ib = blk * 16;
    const int n = ib >> 12;
    const int hw0 = ib & 4095;

    {
        const int r = t & 15, cg = t >> 4;
        const float* fp = feat + (size_t)n * 1048576 + (size_t)(cg * 16) * 4096 + hw0 + r;
        short8 t0, t1;
        #pragma unroll
        for (int ci = 0; ci < 8; ++ci) {
            t0[ci] = f2bf(fp[(size_t)ci * 4096]);
            t1[ci] = f2bf(fp[(size_t)(ci + 8) * 4096]);
        }
        const int sw = (r & 7) << 2;
        *(short8*)(&Xs[r * 256 + ((cg * 2) ^ sw) * 8]) = t0;
        *(short8*)(&Xs[r * 256 + ((cg * 2 + 1) ^ sw) * 8]) = t1;
    }
    __syncthreads();

    const int lane = t & 63;
    const int w = __builtin_amdgcn_readfirstlane(t >> 6);
    const int l15 = lane & 15;
    const int g = lane >> 4;
    const int o0w = w * 96;

    f32x4 acc[6];
    #pragma unroll
    for (int osub = 0; osub < 6; ++osub)
        acc[osub] = *(const f32x4*)(bqkv + o0w + osub * 16 + 4 * g);

    const short* wbase = Wb + (size_t)(o0w + l15) * 256 + g * 8;
    const int xsw = (l15 & 7) << 2;
    #pragma unroll
    for (int kc = 0; kc < 8; ++kc) {
        short8 xf = *(const short8*)(&Xs[l15 * 256 + (((kc * 4 + g) ^ xsw) * 8)]);
        #pragma unroll
        for (int osub = 0; osub < 6; ++osub) {
            short8 wf = *(const short8*)(wbase + (size_t)osub * 16 * 256 + kc * 32);
            acc[osub] = __builtin_amdgcn_mfma_f32_16x16x32_bf16(wf, xf, acc[osub], 0, 0, 0);
        }
    }

    #pragma unroll
    for (int osub = 0; osub < 6; ++osub) {
        const int o0 = o0w + osub * 16;
        const int mat = o0 >> 7;           // 0=q, 1=k, 2=v (wave-uniform)
        const int col = (o0 & 127) + 4 * g;
        if (mat == 0) {
            uint2v pk;
            pk.x = cvt_pk_bf16(acc[osub][0], acc[osub][1]);
            pk.y = cvt_pk_bf16(acc[osub][2], acc[osub][3]);
            *(uint2v*)(Qb + (size_t)(ib + l15) * 128 + col) = pk;
        } else if (mat == 1) {
            uint2v pk;
            pk.x = cvt_pk_bf16(acc[osub][0], acc[osub][1]);
            pk.y = cvt_pk_bf16(acc[osub][2], acc[osub][3]);
            *(uint2v*)(Kb + (size_t)(ib + l15) * 128 + col) = pk;
        } else {
            #pragma unroll
            for (int reg = 0; reg < 4; ++reg)
                VTs[(col + reg) * 16 + l15] = f2bf(acc[osub][reg]);
        }
    }
    __syncthreads();

    // VTs[o][l15i] -> VTg fragment-exact
    {
        const int o = t >> 1, ih = (t & 1) * 8;       // ih in {0,8}
        short8 vv = *(const short8*)(&VTs[o * 16 + ih]);
        const int jt = ib >> 5;
        const int u = (ib >> 4) & 1;
        const int g0 = ih >> 2;                       // 0 or 2
        short* vb = VTg + (size_t)jt * 4096 + (o >> 4) * 512 + (o & 15) * 8 + 4 * u;
        uint4v q = __builtin_bit_cast(uint4v, vv);
        uint2v lo; lo.x = q.x; lo.y = q.y;
        uint2v hi; hi.x = q.z; hi.y = q.w;
        *(uint2v*)(vb + g0 * 128) = lo;
        *(uint2v*)(vb + (g0 + 1) * 128) = hi;
    }
}

// ---------------- flash attention v12: barrier-free wave streams ---------
// R6..R14 evidence: every lockstep variant lands 48-52us with ~9x latency
// slack - the binder is cross-wave coupling, not any single pipe. v12:
// NO LDS, NO barriers in the main loop. Q fragments load straight from L2
// (same pattern as kf, verified since R1); V from fragment-exact VTg
// (R14). Waves split the j-range (w-th quarter of the jq slice), so all
// loads are unique per wave (no L2 redundancy) and all waits are
// compiler-tracked register deps. One __syncthreads at the end merges the
// 4 wave-partials via LDS into the same Opart/Ssb format (epi unchanged).
// Grid: 2048 = ibX(256, 32 i-rows) x jq(8); jq == XCD id.
__global__ __launch_bounds__(256, 2) void attn_kernel(
    const short* __restrict__ Qb, const short* __restrict__ Kb,
    const short* __restrict__ VTg,
    short* __restrict__ Opart, float* __restrict__ Ssb)
{
    __shared__ float Obuf[4][2][16][132];   // 67.6 KB (padded: merge-read banks)
    __shared__ float Sbuf[4][2][16][4];     // 2 KB

    const int tid = threadIdx.x;
    const int lane = tid & 63;
    const int w = __builtin_amdgcn_readfirstlane(tid >> 6);   // 0..3
    const int l15 = lane & 15;
    const int g = lane >> 4;
    const int blk = blockIdx.x;
    const int ibX = blk >> 3;          // 0..255
    const int jq  = blk & 7;           // 0..7 == XCD id
    const int iw  = ibX * 32;
    const int j0  = jq * 1024 + w * 256;   // wave's private j-quarter (8 tiles)

    short8 kf[2][4];                   // shared i-rows: all 4 waves same kf
    #pragma unroll
    for (int iset = 0; iset < 2; ++iset)
        #pragma unroll
        for (int dcq = 0; dcq < 4; ++dcq)
            kf[iset][dcq] = *(const short8*)(Kb + (size_t)(iw + iset * 16 + l15) * 128 + dcq * 32 + g * 8);

    f32x4 O[2][8];
    #pragma unroll
    for (int iset = 0; iset < 2; ++iset)
        #pragma unroll
        for (int dc = 0; dc < 8; ++dc) O[iset][dc] = (f32x4){0.f, 0.f, 0.f, 0.f};
    float s[2] = {0.f, 0.f};

    // ---- per-wave streaming pointers (all loads -> registers) ----
    const short* qp0 = Qb + (size_t)(j0 + l15) * 128 + g * 8;
    const short* qp1 = qp0 + 16 * 128;
    const short* vp0 = VTg + (size_t)(j0 >> 5) * 4096 + lane * 8;
    const short* vp4 = vp0 + 4 * 512;

    short8 qa[2][4], vr[8];
    auto loadQ = [&]() {
        #pragma unroll
        for (int dcq = 0; dcq < 4; ++dcq) {
            qa[0][dcq] = *(const short8*)(qp0 + dcq * 32);
            qa[1][dcq] = *(const short8*)(qp1 + dcq * 32);
        }
        qp0 += 32 * 128;
        qp1 += 32 * 128;
    };
    auto loadV = [&]() {
        #pragma unroll
        for (int dc = 0; dc < 4; ++dc) {
            vr[dc]     = *(const short8*)(vp0 + dc * 512);
            vr[4 + dc] = *(const short8*)(vp4 + dc * 512);
        }
        vp0 += 4096;
        vp4 += 4096;
    };

    loadQ();
    loadV();
    for (int t = 0; t < 8; ++t) {
        // ---- QK^T (consumes qa) ----
        f32x4 sv[2][2];                    // [jh][iset], init -16 (fixed max)
        #pragma unroll
        for (int jh = 0; jh < 2; ++jh)
            #pragma unroll
            for (int iset = 0; iset < 2; ++iset)
                sv[jh][iset] = (f32x4){-16.f, -16.f, -16.f, -16.f};

        __builtin_amdgcn_s_setprio(1);
        #pragma unroll
        for (int dcq = 0; dcq < 4; ++dcq) {
            sv[0][0] = __builtin_amdgcn_mfma_f32_16x16x32_bf16(qa[0][dcq], kf[0][dcq], sv[0][0], 0, 0, 0);
            sv[0][1] = __builtin_amdgcn_mfma_f32_16x16x32_bf16(qa[0][dcq], kf[1][dcq], sv[0][1], 0, 0, 0);
            sv[1][0] = __builtin_amdgcn_mfma_f32_16x16x32_bf16(qa[1][dcq], kf[0][dcq], sv[1][0], 0, 0, 0);
            sv[1][1] = __builtin_amdgcn_mfma_f32_16x16x32_bf16(qa[1][dcq], kf[1][dcq], sv[1][1], 0, 0, 0);
        }
        __builtin_amdgcn_s_setprio(0);

        if (t < 7) loadQ();                // prefetch next Q under softmax+PV

        // ---- softmax (fixed-max, exp2 domain) ----
        short8 pf[2];
        #pragma unroll
        for (int iset = 0; iset < 2; ++iset) {
            float p0[4], p1[4], ps = 0.f;
            #pragma unroll
            for (int e = 0; e < 4; ++e) {
                p0[e] = fexp2(sv[0][iset][e]);
                p1[e] = fexp2(sv[1][iset][e]);
                ps += p0[e] + p1[e];
            }
            s[iset] += ps;                 // per-(i, g) partial
            uint4v pk;
            pk.x = cvt_pk_bf16(p0[0], p0[1]);
            pk.y = cvt_pk_bf16(p0[2], p0[3]);
            pk.z = cvt_pk_bf16(p1[0], p1[1]);
            pk.w = cvt_pk_bf16(p1[2], p1[3]);
            pf[iset] = __builtin_bit_cast(short8, pk);
        }

        // ---- PV (consumes vr; fragment-exact registers) ----
        __builtin_amdgcn_s_setprio(1);
        #pragma unroll
        for (int dc = 0; dc < 8; ++dc) {
            O[0][dc] = __builtin_amdgcn_mfma_f32_16x16x32_bf16(vr[dc], pf[0], O[0][dc], 0, 0, 0);
            O[1][dc] = __builtin_amdgcn_mfma_f32_16x16x32_bf16(vr[dc], pf[1], O[1][dc], 0, 0, 0);
        }
        __builtin_amdgcn_s_setprio(0);

        if (t < 7) loadV();                // prefetch next V under next QK
    }

    // ---- merge the 4 wave-partials via LDS (single barrier) ----
    #pragma unroll
    for (int iset = 0; iset < 2; ++iset) {
        #pragma unroll
        for (int dc = 0; dc < 8; ++dc)
            *(f32x4*)(&Obuf[w][iset][l15][dc * 16 + 4 * g]) = O[iset][dc];
        Sbuf[w][iset][l15][g] = s[iset];
    }
    __syncthreads();

    {
        const int r = tid >> 3;            // 0..31 local i
        const int dch = (tid & 7) * 16;    // d-chunk
        const int iset = r >> 4, lr = r & 15;
        const int i = iw + r;

        float acc[16];
        #pragma unroll
        for (int e = 0; e < 16; ++e) acc[e] = 0.f;
        #pragma unroll
        for (int ww = 0; ww < 4; ++ww) {
            #pragma unroll
            for (int e4 = 0; e4 < 4; ++e4) {
                f32x4 v = *(const f32x4*)(&Obuf[ww][iset][lr][dch + e4 * 4]);
                acc[e4 * 4 + 0] += v[0];
                acc[e4 * 4 + 1] += v[1];
                acc[e4 * 4 + 2] += v[2];
                acc[e4 * 4 + 3] += v[3];
            }
        }
        uint4v pk0, pk1;
        pk0.x = cvt_pk_bf16(acc[0], acc[1]);
        pk0.y = cvt_pk_bf16(acc[2], acc[3]);
        pk0.z = cvt_pk_bf16(acc[4], acc[5]);
        pk0.w = cvt_pk_bf16(acc[6], acc[7]);
        pk1.x = cvt_pk_bf16(acc[8], acc[9]);
        pk1.y = cvt_pk_bf16(acc[10], acc[11]);
        pk1.z = cvt_pk_bf16(acc[12], acc[13]);
        pk1.w = cvt_pk_bf16(acc[14], acc[15]);
        short* op = Opart + ((size_t)i * 8 + jq) * 128 + dch;
        *(uint4v*)(op) = pk0;
        *(uint4v*)(op + 8) = pk1;

        if ((tid & 7) == 0) {
            f32x4 T = {0.f, 0.f, 0.f, 0.f};
            #pragma unroll
            for (int ww = 0; ww < 4; ++ww) {
                f32x4 sv4 = *(const f32x4*)(&Sbuf[ww][iset][lr][0]);
                T[0] += sv4[0]; T[1] += sv4[1]; T[2] += sv4[2]; T[3] += sv4[3];
            }
            *(f32x4*)(Ssb + ((size_t)i * 8 + jq) * 4) = T;
        }
    }
}

// ---------------- epilogue: fused merge + MFMA GEMM (unchanged R13) ------
__global__ __launch_bounds__(256, 4) void epi_kernel(
    const short* __restrict__ Opart, const float* __restrict__ Ssb,
    const short* __restrict__ Wmb, const float* __restrict__ bm,
    const float* __restrict__ feat, float* __restrict__ out)
{
    __shared__ __align__(16) short Ms[16 * 128];   // 4 KB
    const int t = threadIdx.x;
    const int blk = blockIdx.x;
    const int yt = blk & 3;
    const int x = (blk >> 2) & 63;
    const int n = blk >> 8;
    const int y0 = yt * 16;

    // ---- merge: thread (r = t>>4, c = t&15) owns 8 ch of mask row r ----
    {
        const int r = t >> 4, c = t & 15;
        const int i = n * 4096 + (y0 + r) * 64 + x;
        float acc8[8] = {0.f, 0.f, 0.f, 0.f, 0.f, 0.f, 0.f, 0.f};
        #pragma unroll
        for (int q = 0; q < 8; ++q) {
            short8 o = *(const short8*)(Opart + ((size_t)i * 8 + q) * 128 + c * 8);
            #pragma unroll
            for (int e = 0; e < 8; ++e) acc8[e] += bf2f(o[e]);
        }
        // row sum T: 32 partials contiguous; thread c loads 2, reduce 16 lanes
        float2 s2 = *(const float2*)(Ssb + (size_t)i * 32 + c * 2);
        float tp = s2.x + s2.y;
        tp += __shfl_xor(tp, 1);
        tp += __shfl_xor(tp, 2);
        tp += __shfl_xor(tp, 4);
        tp += __shfl_xor(tp, 8);
        const float inv = 1.f / tp;
        uint4v pk;
        pk.x = cvt_pk_bf16(acc8[0] * inv, acc8[1] * inv);
        pk.y = cvt_pk_bf16(acc8[2] * inv, acc8[3] * inv);
        pk.z = cvt_pk_bf16(acc8[4] * inv, acc8[5] * inv);
        pk.w = cvt_pk_bf16(acc8[6] * inv, acc8[7] * inv);
        *(short8*)(&Ms[r * 128 + ((c ^ ((r & 7) << 1)) * 8)]) =
            __builtin_bit_cast(short8, pk);
    }
    __syncthreads();

    const int lane = t & 63;
    const int w = __builtin_amdgcn_readfirstlane(t >> 6);
    const int l15 = lane & 15;
    const int g = lane >> 4;
    const int c0 = w * 64;

    short8 bf[4];
    const int msw = (l15 & 7) << 1;
    #pragma unroll
    for (int dcq = 0; dcq < 4; ++dcq)
        bf[dcq] = *(const short8*)(&Ms[l15 * 128 + (((dcq * 4 + g) ^ msw) * 8)]);

    f32x4 acc[4];
    #pragma unroll
    for (int ct = 0; ct < 4; ++ct)
        acc[ct] = *(const f32x4*)(bm + c0 + ct * 16 + 4 * g);

    const short* wbase = Wmb + (size_t)(c0 + l15) * 128 + g * 8;
    #pragma unroll
    for (int dcq = 0; dcq < 4; ++dcq) {
        #pragma unroll
        for (int ct = 0; ct < 4; ++ct) {
            short8 wf = *(const short8*)(wbase + (size_t)ct * 16 * 128 + dcq * 32);
            acc[ct] = __builtin_amdgcn_mfma_f32_16x16x32_bf16(wf, bf[dcq], acc[ct], 0, 0, 0);
        }
    }

    #pragma unroll
    for (int ct = 0; ct < 4; ++ct) {
        #pragma unroll
        for (int reg = 0; reg < 4; ++reg) {
            const int c = c0 + ct * 16 + 4 * g + reg;
            const size_t oidx = (((size_t)(n * 256 + c) * 64 + x) * 64) + y0 + l15;
            out[oidx] = acc[ct][reg] + feat[oidx];
        }
    }
}

extern "C" void kernel_launch(void* const* d_in, const int* in_sizes, int n_in,
                              void* d_out, int out_size, void* d_ws, size_t ws_size,
                              hipStream_t stream) {
    const float* feat = (const float*)d_in[0];
    const float* Wq = (const float*)d_in[1];
    const float* bq = (const float*)d_in[2];
    const float* Wk = (const float*)d_in[3];
    const float* bk = (const float*)d_in[4];
    const float* Wv = (const float*)d_in[5];
    const float* bv = (const float*)d_in[6];
    const float* Wm = (const float*)d_in[7];
    const float* bm = (const float*)d_in[8];
    float* out = (float*)d_out;

    short* Qb = (short*)d_ws;                      // 8192x128 bf16 (2 MB)
    short* Kb = Qb + 8192 * 128;                   // 2 MB, *log2e
    short* VTg = Kb + 8192 * 128;                  // 256x8x64x8 bf16 frags (2 MB)
    short* Opart = VTg + 8192 * 128;               // 8192 x 8 x 128 bf16 (16 MB)
    float* Ssb = (float*)(Opart + (size_t)8 * 8192 * 128);   // 8192x32 f32 (1 MB)
    float* bqkv = Ssb + (size_t)8192 * 32;         // 1.5 KB
    short* Wb = (short*)(bqkv + 384);              // 384x256 bf16 (192 KB)
    short* Wmb = Wb + 384 * 256;                   // 256x128 bf16 (64 KB)

    hipLaunchKernelGGL(wprep_kernel, dim3(641), dim3(64), 0, stream,
                       Wq, bq, Wk, bk, Wv, bv, Wm, Wb, bqkv, Wmb);
    hipLaunchKernelGGL(proj_kernel, dim3(512), dim3(256), 0, stream,
                       feat, Wb, bqkv, Qb, Kb, VTg);
    hipLaunchKernelGGL(attn_kernel, dim3(2048), dim3(256), 0, stream,
                       Qb, Kb, VTg, Opart, Ssb);
    hipLaunchKernelGGL(epi_kernel, dim3(512), dim3(256), 0, stream,
                       Opart, Ssb, Wmb, bm, feat, out);
}

// Round 16
// 73.842 us; speedup vs baseline: 1.6005x; 1.6005x over previous
//
#include <hip/hip_runtime.h>
#include <hip/hip_bf16.h>

#define LOG2E 1.44269504088896340736f

typedef __attribute__((ext_vector_type(8))) short short8;
typedef __attribute__((ext_vector_type(4))) float f32x4;
typedef __attribute__((ext_vector_type(16))) float f32x16;
typedef __attribute__((ext_vector_type(2))) unsigned int uint2v;
typedef __attribute__((ext_vector_type(4))) unsigned int uint4v;
typedef unsigned int u32;

__device__ __forceinline__ short f2bf(float f) {
    unsigned u = __builtin_bit_cast(unsigned, f);
    unsigned r = (u + 0x7FFFu + ((u >> 16) & 1u)) >> 16;  // RNE
    return (short)r;
}

__device__ __forceinline__ float bf2f(short x) {
    unsigned u = ((unsigned)(unsigned short)x) << 16;
    return __builtin_bit_cast(float, u);
}

__device__ __forceinline__ unsigned cvt_pk_bf16(float lo, float hi) {
    unsigned r;
    asm volatile("v_cvt_pk_bf16_f32 %0, %1, %2" : "=v"(r) : "v"(lo), "v"(hi));
    return r;
}

// raw hardware exp2 (inputs bounded in [-49, 1]: no denormal/range fixup)
__device__ __forceinline__ float fexp2(float x) {
    float r;
    asm("v_exp_f32 %0, %1" : "=v"(r) : "v"(x));
    return r;
}

// ---------------- weight prep: Wb[384][256] bf16 + Wmb[256][128] bf16 ----
__global__ __launch_bounds__(64) void wprep_kernel(
    const float* __restrict__ Wq, const float* __restrict__ bq,
    const float* __restrict__ Wk, const float* __restrict__ bk,
    const float* __restrict__ Wv, const float* __restrict__ bv,
    const float* __restrict__ Wm,
    short* __restrict__ Wb, float* __restrict__ bqkv, short* __restrict__ Wmb)
{
    const int b = blockIdx.x;       // 0..383 W rows, 384 bias, 385..640 Wm rows
    const int t = threadIdx.x;
    if (b < 384) {
        const int mat = b >> 7, row = b & 127;
        const float* src = (mat == 0 ? Wq : mat == 1 ? Wk : Wv) + (size_t)row * 256;
        const float sc = (mat == 1) ? LOG2E : 1.f;
        float4 v = *(const float4*)(src + t * 4);
        uint2v pk;
        pk.x = cvt_pk_bf16(v.x * sc, v.y * sc);
        pk.y = cvt_pk_bf16(v.z * sc, v.w * sc);
        *(uint2v*)(Wb + (size_t)b * 256 + t * 4) = pk;
    } else if (b == 384) {
        for (int e = t; e < 384; e += 64) {
            const int mat = e >> 7;
            const float* bsrc = (mat == 0 ? bq : mat == 1 ? bk : bv);
            bqkv[e] = bsrc[e & 127] * (mat == 1 ? LOG2E : 1.f);
        }
    } else {
        const int row = b - 385;        // 0..255
        float2 v = *(const float2*)(Wm + (size_t)row * 128 + t * 2);
        *(u32*)(Wmb + (size_t)row * 128 + t * 2) = cvt_pk_bf16(v.x, v.y);
    }
}

// ---------------- projection: MFMA GEMM -> fragment-exact Qg/Kg/Vg -------
// 32x32x16 fragment layouts (attn consumes these directly):
//  Qg[jt][kc][lane][e]: Q[jt*32 + (lane&31)][16*kc + 8*(lane>>5) + e]
//  Kg[it][kc][lane][e]: K[it*32 + (lane&31)][16*kc + 8*(lane>>5) + e]
//  Vg[jt][dc][n][lane][e]: V^T[dc*32 + (lane&31)]
//                             [jt*32 + 16n + (e&3) + 4*(lane>>5) + 8*(e>>2)]
// (V column permutation matches the HW-verified 32x32 C/D row map
//  j=(r&3)+8*(r>>2)+4h so PV's B operand packs lane-locally: pf[n]=p[8n..].)
// All attn loads/stages become lane-linear 1KB-coalesced, conflict-free.
__global__ __launch_bounds__(256) void proj_kernel(
    const float* __restrict__ feat, const short* __restrict__ Wb,
    const float* __restrict__ bqkv,
    short* __restrict__ Qg, short* __restrict__ Kg, short* __restrict__ Vg)
{
    __shared__ __align__(16) short Xs[16 * 256];   // 8 KB, swizzled
    __shared__ __align__(16) short VTs[128 * 16];  // 4 KB
    const int t = threadIdx.x;
    const int blk = blockIdx.x;        // 512 blocks
    const int ib = blk * 16;
    const int n = ib >> 12;
    const int hw0 = ib & 4095;

    {
        const int r = t & 15, cg = t >> 4;
        const float* fp = feat + (size_t)n * 1048576 + (size_t)(cg * 16) * 4096 + hw0 + r;
        short8 t0, t1;
        #pragma unroll
        for (int ci = 0; ci < 8; ++ci) {
            t0[ci] = f2bf(fp[(size_t)ci * 4096]);
            t1[ci] = f2bf(fp[(size_t)(ci + 8) * 4096]);
        }
        const int sw = (r & 7) << 2;
        *(short8*)(&Xs[r * 256 + ((cg * 2) ^ sw) * 8]) = t0;
        *(short8*)(&Xs[r * 256 + ((cg * 2 + 1) ^ sw) * 8]) = t1;
    }
    __syncthreads();

    const int lane = t & 63;
    const int w = __builtin_amdgcn_readfirstlane(t >> 6);
    const int l15 = lane & 15;
    const int g = lane >> 4;
    const int o0w = w * 96;

    f32x4 acc[6];
    #pragma unroll
    for (int osub = 0; osub < 6; ++osub)
        acc[osub] = *(const f32x4*)(bqkv + o0w + osub * 16 + 4 * g);

    const short* wbase = Wb + (size_t)(o0w + l15) * 256 + g * 8;
    const int xsw = (l15 & 7) << 2;
    #pragma unroll
    for (int kc = 0; kc < 8; ++kc) {
        short8 xf = *(const short8*)(&Xs[l15 * 256 + (((kc * 4 + g) ^ xsw) * 8)]);
        #pragma unroll
        for (int osub = 0; osub < 6; ++osub) {
            short8 wf = *(const short8*)(wbase + (size_t)osub * 16 * 256 + kc * 32);
            acc[osub] = __builtin_amdgcn_mfma_f32_16x16x32_bf16(wf, xf, acc[osub], 0, 0, 0);
        }
    }

    #pragma unroll
    for (int osub = 0; osub < 6; ++osub) {
        const int o0 = o0w + osub * 16;
        const int mat = o0 >> 7;           // 0=q, 1=k, 2=v (wave-uniform)
        if (mat < 2) {
            // fragment-exact write: ch0..ch0+3 consecutive within one e-quad
            const int ch0 = (o0 & 127) + 4 * g;
            const int kc = ch0 >> 4;
            const int hh = (ch0 >> 3) & 1;
            const int e0 = ch0 & 7;            // 0 or 4
            const int j = ib + l15;
            short* dst = (mat == 0 ? Qg : Kg)
                + (size_t)(j >> 5) * 4096 + kc * 512 + ((j & 31) + 32 * hh) * 8 + e0;
            uint2v pk;
            pk.x = cvt_pk_bf16(acc[osub][0], acc[osub][1]);
            pk.y = cvt_pk_bf16(acc[osub][2], acc[osub][3]);
            *(uint2v*)dst = pk;
        } else {
            const int col = (o0 & 127) + 4 * g;
            #pragma unroll
            for (int reg = 0; reg < 4; ++reg)
                VTs[(col + reg) * 16 + l15] = f2bf(acc[osub][reg]);
        }
    }
    __syncthreads();

    // VTs[d][i16] -> Vg fragment-exact
    {
        const int o = t >> 1, ih = (t & 1) * 8;       // ih in {0,8}
        short8 vv = *(const short8*)(&VTs[o * 16 + ih]);
        const int jt = ib >> 5;
        const int nn = (ib >> 4) & 1;
        short* vb = Vg + (size_t)jt * 4096 + (o >> 5) * 1024 + nn * 512
                      + (o & 31) * 8 + (ih >> 1);
        uint4v q = __builtin_bit_cast(uint4v, vv);
        uint2v lo; lo.x = q.x; lo.y = q.y;   // i16 = ih..ih+3   -> h=0 slots
        uint2v hi; hi.x = q.z; hi.y = q.w;   // i16 = ih+4..ih+7 -> h=1 slots
        *(uint2v*)(vb) = lo;
        *(uint2v*)(vb + 256) = hi;
    }
}

// ---------------- flash attention v13: 32x32x16 shape, linear LDS --------
// R13 loop/sync structure (proven: absmax 0.0156, 47.7us) with:
//  - 32x32x16 MFMA: 16 instrs/wave-tile (was 32), rate 2495 vs 2075 TF
//  - fragment-exact Qg/Vg: staging = contiguous 1KB coalesced segments,
//    LDS reads all `base + lane*16` (canonical conflict-free), no swizzle
//  - wave = 32 i (one 32x32 tile), lane owns i = l&31, 16 j's -> s scalar
// Grid: 512 = ibX(64) x jq(8); jq == XCD id; 4x16KB ring, barrier per 2 tiles.
__global__ __launch_bounds__(256, 2) void attn_kernel(
    const short* __restrict__ Qg, const short* __restrict__ Kg,
    const short* __restrict__ Vg,
    short* __restrict__ Opart, float* __restrict__ Ssb)
{
    __shared__ __align__(16) char smem[65536];   // 4 x (8K Q + 8K V)

    const int tid = threadIdx.x;
    const int lane = tid & 63;
    const int w = __builtin_amdgcn_readfirstlane(tid >> 6);   // 0..3
    const int l31 = lane & 31;
    const int h = lane >> 5;
    const int blk = blockIdx.x;
    const int ibX = blk >> 3;          // 0..63
    const int jq  = blk & 7;           // 0..7 == XCD id
    const int iw  = ibX * 128 + w * 32;
    const int j0  = jq * 1024;

    // K fragments (8 kc), 1KB-coalesced from L2
    short8 kf[8];
    {
        const short* kp = Kg + (size_t)(iw >> 5) * 4096 + lane * 8;
        #pragma unroll
        for (int kc = 0; kc < 8; ++kc) kf[kc] = *(const short8*)(kp + kc * 512);
    }

    f32x16 O[4];
    #pragma unroll
    for (int dc = 0; dc < 4; ++dc)
        #pragma unroll
        for (int e = 0; e < 16; ++e) O[dc][e] = 0.f;
    float s = 0.f;

    // staging pointers: tiles are 4096-short contiguous blobs
    const short* srcQ = Qg + (size_t)(j0 >> 5) * 4096 + w * 512 + lane * 8;
    const short* srcV = Vg + (size_t)(j0 >> 5) * 4096 + w * 512 + lane * 8;

    auto stage = [&](int quarter) {
        char* base = smem + quarter * 16384;
        __builtin_amdgcn_global_load_lds(
            (const __attribute__((address_space(1))) u32*)(const void*)srcQ,
            (__attribute__((address_space(3))) u32*)(void*)(base + w * 1024), 16, 0, 0);
        __builtin_amdgcn_global_load_lds(
            (const __attribute__((address_space(1))) u32*)(const void*)(srcQ + 2048),
            (__attribute__((address_space(3))) u32*)(void*)(base + (4 + w) * 1024), 16, 0, 0);
        __builtin_amdgcn_global_load_lds(
            (const __attribute__((address_space(1))) u32*)(const void*)srcV,
            (__attribute__((address_space(3))) u32*)(void*)(base + 8192 + w * 1024), 16, 0, 0);
        __builtin_amdgcn_global_load_lds(
            (const __attribute__((address_space(1))) u32*)(const void*)(srcV + 2048),
            (__attribute__((address_space(3))) u32*)(void*)(base + 8192 + (4 + w) * 1024), 16, 0, 0);
        srcQ += 4096;
        srcV += 4096;
    };

    auto compute32 = [&](const char* base) {
        const char* Qt = base;
        const char* Vt = base + 8192;

        f32x16 sv;
        #pragma unroll
        for (int e = 0; e < 16; ++e) sv[e] = -16.f;   // fixed max

        __builtin_amdgcn_s_setprio(1);
        #pragma unroll
        for (int kc = 0; kc < 8; ++kc) {
            short8 qa = *(const short8*)(Qt + kc * 1024 + lane * 16);
            sv = __builtin_amdgcn_mfma_f32_32x32x16_bf16(qa, kf[kc], sv, 0, 0, 0);
        }
        __builtin_amdgcn_s_setprio(0);

        float p[16], ps = 0.f;
        #pragma unroll
        for (int r = 0; r < 16; ++r) { p[r] = fexp2(sv[r]); ps += p[r]; }
        s += ps;
        short8 pf0, pf1;
        {
            uint4v a, b;
            a.x = cvt_pk_bf16(p[0], p[1]);  a.y = cvt_pk_bf16(p[2], p[3]);
            a.z = cvt_pk_bf16(p[4], p[5]);  a.w = cvt_pk_bf16(p[6], p[7]);
            b.x = cvt_pk_bf16(p[8], p[9]);  b.y = cvt_pk_bf16(p[10], p[11]);
            b.z = cvt_pk_bf16(p[12], p[13]); b.w = cvt_pk_bf16(p[14], p[15]);
            pf0 = __builtin_bit_cast(short8, a);
            pf1 = __builtin_bit_cast(short8, b);
        }

        __builtin_amdgcn_s_setprio(1);
        #pragma unroll
        for (int dc = 0; dc < 4; ++dc) {
            short8 va0 = *(const short8*)(Vt + dc * 2048 + lane * 16);
            short8 va1 = *(const short8*)(Vt + dc * 2048 + 1024 + lane * 16);
            O[dc] = __builtin_amdgcn_mfma_f32_32x32x16_bf16(va0, pf0, O[dc], 0, 0, 0);
            O[dc] = __builtin_amdgcn_mfma_f32_32x32x16_bf16(va1, pf1, O[dc], 0, 0, 0);
        }
        __builtin_amdgcn_s_setprio(0);
    };

    // prologue: tiles 0,1 -> quarters 0,1
    stage(0);
    stage(1);
    __syncthreads();
    // pair loop over 32 tiles: ONE barrier per 2 tiles (ring distance 4)
    for (int tt = 0; tt < 32; tt += 2) {
        if (tt + 2 < 32) {
            stage((tt + 2) & 3);
            stage((tt + 3) & 3);
        }
        compute32(smem + (tt & 3) * 16384);
        compute32(smem + ((tt + 1) & 3) * 16384);
        __syncthreads();                 // drains staged loads too
    }

    // writeback: lane owns i = iw + l31; d = dc*32 + (reg&3)+8*(reg>>2)+4h
    {
        const int i = iw + l31;
        short* op = Opart + ((size_t)i * 8 + jq) * 128;
        #pragma unroll
        for (int dc = 0; dc < 4; ++dc) {
            #pragma unroll
            for (int q4 = 0; q4 < 4; ++q4) {
                uint2v pk;
                pk.x = cvt_pk_bf16(O[dc][4 * q4 + 0], O[dc][4 * q4 + 1]);
                pk.y = cvt_pk_bf16(O[dc][4 * q4 + 2], O[dc][4 * q4 + 3]);
                *(uint2v*)(op + dc * 32 + q4 * 8 + 4 * h) = pk;
            }
        }
        Ssb[((size_t)i * 8 + jq) * 2 + h] = s;    // 16 partials per row i
    }
}

// ---------------- epilogue: fused merge + MFMA GEMM ----------------------
__global__ __launch_bounds__(256, 4) void epi_kernel(
    const short* __restrict__ Opart, const float* __restrict__ Ssb,
    const short* __restrict__ Wmb, const float* __restrict__ bm,
    const float* __restrict__ feat, float* __restrict__ out)
{
    __shared__ __align__(16) short Ms[16 * 128];   // 4 KB
    const int t = threadIdx.x;
    const int blk = blockIdx.x;
    const int yt = blk & 3;
    const int x = (blk >> 2) & 63;
    const int n = blk >> 8;
    const int y0 = yt * 16;

    // ---- merge: thread (r = t>>4, c = t&15) owns 8 ch of mask row r ----
    {
        const int r = t >> 4, c = t & 15;
        const int i = n * 4096 + (y0 + r) * 64 + x;
        float acc8[8] = {0.f, 0.f, 0.f, 0.f, 0.f, 0.f, 0.f, 0.f};
        #pragma unroll
        for (int q = 0; q < 8; ++q) {
            short8 o = *(const short8*)(Opart + ((size_t)i * 8 + q) * 128 + c * 8);
            #pragma unroll
            for (int e = 0; e < 8; ++e) acc8[e] += bf2f(o[e]);
        }
        // row sum: 16 contiguous partials; thread c loads 1, 16-lane reduce
        float tp = Ssb[(size_t)i * 16 + c];
        tp += __shfl_xor(tp, 1);
        tp += __shfl_xor(tp, 2);
        tp += __shfl_xor(tp, 4);
        tp += __shfl_xor(tp, 8);
        const float inv = 1.f / tp;
        uint4v pk;
        pk.x = cvt_pk_bf16(acc8[0] * inv, acc8[1] * inv);
        pk.y = cvt_pk_bf16(acc8[2] * inv, acc8[3] * inv);
        pk.z = cvt_pk_bf16(acc8[4] * inv, acc8[5] * inv);
        pk.w = cvt_pk_bf16(acc8[6] * inv, acc8[7] * inv);
        *(short8*)(&Ms[r * 128 + ((c ^ ((r & 7) << 1)) * 8)]) =
            __builtin_bit_cast(short8, pk);
    }
    __syncthreads();

    const int lane = t & 63;
    const int w = __builtin_amdgcn_readfirstlane(t >> 6);
    const int l15 = lane & 15;
    const int g = lane >> 4;
    const int c0 = w * 64;

    short8 bf[4];
    const int msw = (l15 & 7) << 1;
    #pragma unroll
    for (int dcq = 0; dcq < 4; ++dcq)
        bf[dcq] = *(const short8*)(&Ms[l15 * 128 + (((dcq * 4 + g) ^ msw) * 8)]);

    f32x4 acc[4];
    #pragma unroll
    for (int ct = 0; ct < 4; ++ct)
        acc[ct] = *(const f32x4*)(bm + c0 + ct * 16 + 4 * g);

    const short* wbase = Wmb + (size_t)(c0 + l15) * 128 + g * 8;
    #pragma unroll
    for (int dcq = 0; dcq < 4; ++dcq) {
        #pragma unroll
        for (int ct = 0; ct < 4; ++ct) {
            short8 wf = *(const short8*)(wbase + (size_t)ct * 16 * 128 + dcq * 32);
            acc[ct] = __builtin_amdgcn_mfma_f32_16x16x32_bf16(wf, bf[dcq], acc[ct], 0, 0, 0);
        }
    }

    #pragma unroll
    for (int ct = 0; ct < 4; ++ct) {
        #pragma unroll
        for (int reg = 0; reg < 4; ++reg) {
            const int c = c0 + ct * 16 + 4 * g + reg;
            const size_t oidx = (((size_t)(n * 256 + c) * 64 + x) * 64) + y0 + l15;
            out[oidx] = acc[ct][reg] + feat[oidx];
        }
    }
}

extern "C" void kernel_launch(void* const* d_in, const int* in_sizes, int n_in,
                              void* d_out, int out_size, void* d_ws, size_t ws_size,
                              hipStream_t stream) {
    const float* feat = (const float*)d_in[0];
    const float* Wq = (const float*)d_in[1];
    const float* bq = (const float*)d_in[2];
    const float* Wk = (const float*)d_in[3];
    const float* bk = (const float*)d_in[4];
    const float* Wv = (const float*)d_in[5];
    const float* bv = (const float*)d_in[6];
    const float* Wm = (const float*)d_in[7];
    const float* bm = (const float*)d_in[8];
    float* out = (float*)d_out;

    short* Qg = (short*)d_ws;                      // 256 tiles x 4096 bf16 (2 MB)
    short* Kg = Qg + 8192 * 128;                   // 2 MB (k, *log2e folded)
    short* Vg = Kg + 8192 * 128;                   // 2 MB fragment-exact
    short* Opart = Vg + 8192 * 128;                // 8192 x 8 x 128 bf16 (16 MB)
    float* Ssb = (float*)(Opart + (size_t)8 * 8192 * 128);   // 8192x16 f32 (512 KB)
    float* bqkv = Ssb + (size_t)8192 * 16;         // 1.5 KB
    short* Wb = (short*)(bqkv + 384);              // 384x256 bf16 (192 KB)
    short* Wmb = Wb + 384 * 256;                   // 256x128 bf16 (64 KB)

    hipLaunchKernelGGL(wprep_kernel, dim3(641), dim3(64), 0, stream,
                       Wq, bq, Wk, bk, Wv, bv, Wm, Wb, bqkv, Wmb);
    hipLaunchKernelGGL(proj_kernel, dim3(512), dim3(256), 0, stream,
                       feat, Wb, bqkv, Qg, Kg, Vg);
    hipLaunchKernelGGL(attn_kernel, dim3(512), dim3(256), 0, stream,
                       Qg, Kg, Vg, Opart, Ssb);
    hipLaunchKernelGGL(epi_kernel, dim3(512), dim3(256), 0, stream,
                       Opart, Ssb, Wmb, bm, feat, out);
}